// Round 17
// baseline (165.400 us; speedup 1.0000x reference)
//
#include <hip/hip_runtime.h>

#define DEV __device__ __forceinline__

typedef unsigned short u16;
typedef __attribute__((ext_vector_type(8))) short bf16x8;
typedef __attribute__((ext_vector_type(4))) float f32x4;
typedef __attribute__((ext_vector_type(4))) unsigned int u32x4;
typedef __attribute__((ext_vector_type(2))) unsigned int u32x2;

// round-to-nearest-even f32 -> bf16
DEV u16 f2bf(float f) {
  union { float f; unsigned u; } un; un.f = f;
  unsigned r = un.u + 0x7fffu + ((un.u >> 16) & 1u);
  return (u16)(r >> 16);
}

DEV void gload16(const void* g, void* l) {
  __builtin_amdgcn_global_load_lds((const __attribute__((address_space(1))) void*)g,
                                   (__attribute__((address_space(3))) void*)l, 16, 0, 0);
}

template <int N>
DEV void vm_wait() { asm volatile("s_waitcnt vmcnt(%0)" :: "n"(N) : "memory"); }

DEV float blk_sum(float v, volatile float* sb) {
#pragma unroll
  for (int o = 32; o; o >>= 1) v += __shfl_xor(v, o);
  __syncthreads();
  if ((threadIdx.x & 63) == 0) sb[threadIdx.x >> 6] = v;
  __syncthreads();
  return sb[0] + sb[1] + sb[2] + sb[3];
}

// ---------------- LayerNorm (row = 768) -> bf16 ----------------
__global__ __launch_bounds__(256) void ln_kernel(const float* __restrict__ x,
                                                 const float* __restrict__ g,
                                                 const float* __restrict__ b,
                                                 u16* __restrict__ y) {
  __shared__ float sb[4];
  const size_t row = blockIdx.x;
  const float* xr = x + row * 768;
  const int t = threadIdx.x;
  float v0 = xr[t], v1 = xr[t + 256], v2 = xr[t + 512];
  float mean = blk_sum(v0 + v1 + v2, sb) * (1.0f / 768.0f);
  float d0 = v0 - mean, d1 = v1 - mean, d2 = v2 - mean;
  float var = blk_sum(d0 * d0 + d1 * d1 + d2 * d2, sb) * (1.0f / 768.0f);
  float inv = rsqrtf(var + 1e-5f);
  u16* yr = y + row * 768;
  yr[t]       = f2bf(d0 * inv * g[t]       + b[t]);
  yr[t + 256] = f2bf(d1 * inv * g[t + 256] + b[t + 256]);
  yr[t + 512] = f2bf(d2 * inv * g[t + 512] + b[t + 512]);
}

// ---------------- all-weights transpose+convert + LN1, ONE dispatch ----------------
// Blocks 0..1727: 64x64 transpose tiles, in[K][N] f32 -> out[N][K] bf16.
// Blocks 1728..3775: LN1 over x rows.
__global__ __launch_bounds__(256) void wt_all(
    const float* __restrict__ wq, const float* __restrict__ wk,
    const float* __restrict__ wv, const float* __restrict__ wo,
    const float* __restrict__ w1, const float* __restrict__ w2,
    u16* __restrict__ oq, u16* __restrict__ ok, u16* __restrict__ ov,
    u16* __restrict__ oo, u16* __restrict__ o1, u16* __restrict__ o2,
    const float* __restrict__ x, const float* __restrict__ ln_g,
    const float* __restrict__ ln_b, u16* __restrict__ y1) {
  __shared__ float tile[64][65];
  __shared__ float sb[4];
  const int id = blockIdx.x;

  if (id >= 1728) {  // ---- LN1 rows ----
    const size_t row = id - 1728;
    const float* xr = x + row * 768;
    const int t = threadIdx.x;
    float v0 = xr[t], v1 = xr[t + 256], v2 = xr[t + 512];
    float mean = blk_sum(v0 + v1 + v2, sb) * (1.0f / 768.0f);
    float d0 = v0 - mean, d1 = v1 - mean, d2 = v2 - mean;
    float var = blk_sum(d0 * d0 + d1 * d1 + d2 * d2, sb) * (1.0f / 768.0f);
    float inv = rsqrtf(var + 1e-5f);
    u16* yr = y1 + row * 768;
    yr[t]       = f2bf(d0 * inv * ln_g[t]       + ln_b[t]);
    yr[t + 256] = f2bf(d1 * inv * ln_g[t + 256] + ln_b[t + 256]);
    yr[t + 512] = f2bf(d2 * inv * ln_g[t + 512] + ln_b[t + 512]);
    return;
  }

  const float* in;
  u16* out;
  int K, N, t, nx;
  if (id < 576) {
    int s = id / 144;
    t = id % 144;
    K = 768; N = 768; nx = 12;
    in  = (s == 0) ? wq : (s == 1) ? wk : (s == 2) ? wv : wo;
    out = (s == 0) ? oq : (s == 1) ? ok : (s == 2) ? ov : oo;
  } else if (id < 1152) {
    t = id - 576; in = w1; out = o1; K = 768; N = 3072; nx = 48;
  } else {
    t = id - 1152; in = w2; out = o2; K = 3072; N = 768; nx = 12;
  }
  const int yt = t / nx;
  const int xt = t - yt * nx;
  const int n0 = xt * 64, k0 = yt * 64;
  const int tx = threadIdx.x & 15, ty = threadIdx.x >> 4;  // 16 x 16

#pragma unroll
  for (int p = 0; p < 4; p++) {
    int r = p * 16 + ty;
    f32x4 v = *(const f32x4*)&in[(size_t)(k0 + r) * N + n0 + tx * 4];
    tile[r][tx * 4 + 0] = v[0];
    tile[r][tx * 4 + 1] = v[1];
    tile[r][tx * 4 + 2] = v[2];
    tile[r][tx * 4 + 3] = v[3];
  }
  __syncthreads();
#pragma unroll
  for (int p = 0; p < 4; p++) {
    int orow = p * 16 + ty;
    unsigned pk0 = (unsigned)f2bf(tile[tx * 4 + 0][orow]) |
                   ((unsigned)f2bf(tile[tx * 4 + 1][orow]) << 16);
    unsigned pk1 = (unsigned)f2bf(tile[tx * 4 + 2][orow]) |
                   ((unsigned)f2bf(tile[tx * 4 + 3][orow]) << 16);
    *(u32x2*)&out[(size_t)(n0 + orow) * K + k0 + tx * 4] = (u32x2){pk0, pk1};
  }
}

// ---------------- fused poly-norm attention (R9 body + T1 remap + negated-xs phase 2) --
// Grid: (64, 24) = 1536 blocks, 512 thr = 8 waves, 2 barriers. T1 remap: id2 =
// (id&7)*192 + (id>>3) gives each XCD 192 consecutive tiles = 3 heads (L2-resident K/V).
// Phase 2 instruction diet (R17): bf16 unpack folds a sign flip (XOR 0x80000000) so
// xs = -score and base = xs - c costs ONE op; s2/s3 use 4-way reassociated partial
// accumulators to cut the serial FP-add chain 4x. Math trajectory identical to the
// reference modulo ulp-level reassociation (Newton self-corrects; weights shift << bf16 ulp).
// NOTE (R10/R11): in-kernel tile loops inflate VGPR 32->60-80; single tile per block.
__global__ __launch_bounds__(512) void fused_attn(const u16* __restrict__ qkv,
                                                  const u16* __restrict__ vT,
                                                  u16* __restrict__ attn) {
  __shared__ __align__(16) u16 wlds[16 * 1024];  // 32KB, XOR-swizzled (scores, then weights)

  const int tid = threadIdx.x;
  const int w = tid >> 6, l = tid & 63;
  const int g = l >> 4, lr = l & 15;
  const int id = blockIdx.y * 64 + blockIdx.x;          // flat dispatch id (x fastest)
  const int id2 = (id & 7) * 192 + (id >> 3);           // XCD-contiguous tile id
  const int bh = id2 >> 6, b = bh / 12, h = bh % 12;
  const int q0 = (id2 & 63) * 16;

  // ---- QK^T (q pre-scaled by 1/8 in the QKV GEMM) ----
  const u16* qrow = qkv + (size_t)(b * 1024 + q0 + lr) * 2304 + h * 64;
  const u16* krow = qkv + (size_t)(b * 1024 + w * 128 + lr) * 2304 + 768 + h * 64;

  bf16x8 af[2];
  af[0] = *(const bf16x8*)(qrow + g * 8);
  af[1] = *(const bf16x8*)(qrow + 32 + g * 8);

  f32x4 acc[8];
#pragma unroll
  for (int n = 0; n < 8; n++) acc[n] = (f32x4){0.f, 0.f, 0.f, 0.f};

#pragma unroll
  for (int n = 0; n < 8; n++) {
    bf16x8 b0 = *(const bf16x8*)(krow + n * 16 * 2304 + g * 8);
    bf16x8 b1 = *(const bf16x8*)(krow + n * 16 * 2304 + 32 + g * 8);
    acc[n] = __builtin_amdgcn_mfma_f32_16x16x32_bf16(af[0], b0, acc[n], 0, 0, 0);
    acc[n] = __builtin_amdgcn_mfma_f32_16x16x32_bf16(af[1], b1, acc[n], 0, 0, 0);
  }
  // lane holds scores for rows g*4 + r (q-local), cols w*128 + n*16 + lr

  // ---- scatter scores (bf16) into swizzled LDS ----
#pragma unroll
  for (int n = 0; n < 8; n++)
#pragma unroll
    for (int r = 0; r < 4; r++) {
      int row = g * 4 + r;
      int col = w * 128 + n * 16 + lr;
      unsigned off = (unsigned)(row * 2048 + col * 2);
      off ^= (unsigned)(row & 7) << 4;
      *(u16*)((char*)wlds + off) = f2bf(acc[n][r]);
    }
  __syncthreads();  // barrier 1

  // ---- chunk read: thread owns row = tid>>5, cols (tid&31)*32 .. +31 ----
  // unpack with folded sign flip: xs[i] = -score[i]
  const int crow = tid >> 5, l32 = tid & 31;
  const unsigned cswz = (unsigned)(crow & 7) << 4;
  const unsigned cbase = (unsigned)(crow * 2048 + l32 * 64);
  float xs[32];
#pragma unroll
  for (int j = 0; j < 4; j++) {
    u32x4 raw = *(const u32x4*)((const char*)wlds + ((cbase + j * 16u) ^ cswz));
#pragma unroll
    for (int e = 0; e < 4; e++) {
      union { unsigned u; float f; } lo, hi;
      lo.u = (raw[e] << 16) ^ 0x80000000u;
      hi.u = (raw[e] & 0xffff0000u) ^ 0x80000000u;
      xs[j * 8 + e * 2] = lo.f;
      xs[j * 8 + e * 2 + 1] = hi.f;
    }
  }

  // ---- c0 = min(-score) - 1 = min(xs) - 1 (31 fmin + 5 half-wave shfl) ----
  float mn = xs[0];
#pragma unroll
  for (int i = 1; i < 32; i++) mn = fminf(mn, xs[i]);
#pragma unroll
  for (int o = 1; o < 32; o <<= 1) mn = fminf(mn, __shfl_xor(mn, o));
  float c = mn - 1.0f;

  // ---- 6 Newton iterations: base = xs - c (one op), 4-way partial sums ----
#pragma unroll 1
  for (int it = 0; it < 6; it++) {
    float s2p[4] = {0.f, 0.f, 0.f, 0.f};
    float s3p[4] = {0.f, 0.f, 0.f, 0.f};
#pragma unroll
    for (int i = 0; i < 32; i++) {
      float rr = __builtin_amdgcn_rcpf(xs[i] - c);  // 1/base, base >= 1
      float r2 = rr * rr;
      s2p[i & 3] += r2;
      s3p[i & 3] = fmaf(r2, rr, s3p[i & 3]);
    }
    float s2 = (s2p[0] + s2p[1]) + (s2p[2] + s2p[3]);
    float s3 = (s3p[0] + s3p[1]) + (s3p[2] + s3p[3]);
#pragma unroll
    for (int o = 1; o < 32; o <<= 1) {
      s2 += __shfl_xor(s2, o);
      s3 += __shfl_xor(s3, o);
    }
    c -= (s2 - 1.0f) * __builtin_amdgcn_rcpf(2.0f * s3 + 1e-8f);
  }

  // ---- weights = base^-2 -> bf16, written back in place (same addresses) ----
#pragma unroll
  for (int j = 0; j < 4; j++) {
    u32x4 outv;
#pragma unroll
    for (int e = 0; e < 4; e++) {
      float r0 = __builtin_amdgcn_rcpf(xs[j * 8 + e * 2] - c);
      float r1 = __builtin_amdgcn_rcpf(xs[j * 8 + e * 2 + 1] - c);
      outv[e] = (unsigned)f2bf(r0 * r0) | ((unsigned)f2bf(r1 * r1) << 16);
    }
    *(u32x4*)((char*)wlds + ((cbase + j * 16u) ^ cswz)) = outv;
  }
  __syncthreads();  // barrier 2

  // ---- PV: waves 0..3 only — wave w: O[16][w*16..+16] over full K=1024 ----
  if (w < 4) {
    const int nf = w;
    const u16* vrow = vT + (size_t)(bh * 64 + nf * 16 + lr) * 1024;
    const unsigned swz = (unsigned)(lr & 7) << 4;
    const unsigned abase = (unsigned)(lr * 2048);
    f32x4 oacc = (f32x4){0.f, 0.f, 0.f, 0.f};
#pragma unroll
    for (int ks = 0; ks < 32; ks++) {
      // full-address XOR matching the write-side involution
      bf16x8 afr = *(const bf16x8*)((const char*)wlds +
                                    ((abase + (unsigned)(ks * 64 + g * 16)) ^ swz));
      bf16x8 bfr = *(const bf16x8*)(vrow + ks * 32 + g * 8);
      oacc = __builtin_amdgcn_mfma_f32_16x16x32_bf16(afr, bfr, oacc, 0, 0, 0);
    }
    u16* orow = attn + (size_t)(b * 1024 + q0 + g * 4) * 768 + h * 64 + nf * 16 + lr;
#pragma unroll
    for (int r = 0; r < 4; r++) orow[(size_t)r * 768] = f2bf(oacc[r]);
  }
}

// ---------------- split-K reduce (bf16 partials): out = sum(p[z]) + bias + res ----------------
__global__ __launch_bounds__(256) void splitk_reduce(const u16* __restrict__ p,
                                                     const float* __restrict__ bias,
                                                     const float* __restrict__ res,
                                                     float* __restrict__ out) {
  const size_t S = 2048ull * 768;
  size_t i = ((size_t)blockIdx.x * 256 + threadIdx.x) * 4;
  float a0 = 0.f, a1 = 0.f, a2 = 0.f, a3 = 0.f;
#pragma unroll
  for (int z = 0; z < 4; z++) {
    u32x2 raw = *(const u32x2*)&p[i + z * S];
    union { unsigned u; float f; } v0, v1, v2, v3;
    v0.u = raw[0] << 16;
    v1.u = raw[0] & 0xffff0000u;
    v2.u = raw[1] << 16;
    v3.u = raw[1] & 0xffff0000u;
    a0 += v0.f; a1 += v1.f; a2 += v2.f; a3 += v3.f;
  }
  int col = (int)(i % 768);
  f32x4 bv = *(const f32x4*)&bias[col];
  f32x4 rv = *(const f32x4*)&res[i];
  f32x4 v = (f32x4){a0, a1, a2, a3} + bv + rv;
  *(f32x4*)&out[i] = v;
}

// ---------------- pipelined MFMA GEMM: C = A[M][K] * Bt[N][K]^T ----------------
// BM in {64,128}. BM=128: 4 waves as 2x2, BN = 2*WN*16. BM=64: 4 waves as 1x4, BN = 4*WN*16.
// 3-buffer LDS, 2-deep global_load_lds prefetch, counted vmcnt, raw s_barrier (no drain).
// EPI: 0=fused QKV (bias-select + q scale, bf16 out; v-blocks scatter into vT via 'res'),
//      1=f32 plain, 2=bf16 plain, 3=f32 + bias + residual, 4=GELU(acc+bias) bf16
template <int BM, int WN, int EPI>
__global__ __launch_bounds__(256) void gemm_bt(
    const u16* __restrict__ A, int lda, long long sAb, long long sAh,
    const u16* __restrict__ B0, const u16* __restrict__ B1, const u16* __restrict__ B2,
    int ldb, long long sBb, long long sBh,
    void* __restrict__ Cv, int ldc, long long sCb, long long sCh,
    const float* __restrict__ bias0, const float* __restrict__ bias1,
    const float* __restrict__ bias2, const float* __restrict__ res, int K) {
  constexpr int WCOL = (BM == 128) ? 2 : 4;
  constexpr int BN = WCOL * WN * 16;
  constexpr int NA = BM / 64;
  constexpr int NB = BN / 64;
  constexpr int LT = NA + NB;
  __shared__ __align__(16) u16 lds_a[3][BM * 32];
  __shared__ __align__(16) u16 lds_b[3][BN * 32];

  const int zb = blockIdx.z / 12, zh = blockIdx.z % 12;
  A += zb * sAb + zh * sAh;

  const int colbase = blockIdx.y * BN;
  const u16* B = B0;
  const float* bias = bias0;
  int biasoff = 0;
  float qscale = 1.0f;
  int sel = 0;
  if (EPI == 0) {
    sel = colbase / 768;
    B = (sel == 0) ? B0 : ((sel == 1) ? B1 : B2);
    bias = (sel == 0) ? bias0 : ((sel == 1) ? bias1 : bias2);
    biasoff = sel * 768;
    qscale = (sel == 0) ? 0.125f : 1.0f;  // 1/sqrt(64) on q only
  }
  B += zb * sBb + zh * sBh;

  const int tid = threadIdx.x;
  const size_t ldab = (size_t)lda * 2, ldbb = (size_t)ldb * 2;
  const char* Abase = (const char*)(A + (size_t)blockIdx.x * BM * lda);
  const char* Bbase = (const char*)(B + (size_t)(colbase - biasoff) * ldb);

  const char* ap[NA];
  const char* bp[NB];
#pragma unroll
  for (int j = 0; j < NA; j++) {
    int lin = (j * 256 + tid) * 16;
    ap[j] = Abase + (size_t)(lin >> 6) * ldab + (lin & 63);
  }
#pragma unroll
  for (int j = 0; j < NB; j++) {
    int lin = (j * 256 + tid) * 16;
    bp[j] = Bbase + (size_t)(lin >> 6) * ldbb + (lin & 63);
  }

  auto stage = [&](int buf) {
#pragma unroll
    for (int j = 0; j < NA; j++) {
      gload16(ap[j], (char*)&lds_a[buf][0] + (j * 256 + tid) * 16);
      ap[j] += 64;
    }
#pragma unroll
    for (int j = 0; j < NB; j++) {
      gload16(bp[j], (char*)&lds_b[buf][0] + (j * 256 + tid) * 16);
      bp[j] += 64;
    }
  };

  f32x4 acc[4][WN];
#pragma unroll
  for (int m = 0; m < 4; m++)
#pragma unroll
    for (int n = 0; n < WN; n++) acc[m][n] = (f32x4){0.f, 0.f, 0.f, 0.f};

  const int w = tid >> 6, l = tid & 63;
  const int wm = (BM == 128) ? (w >> 1) : 0;
  const int wn = (BM == 128) ? (w & 1) : w;
  const int lr = l & 15, kg = l >> 4;

  const int nt = K / 32;
  stage(0);
  if (nt > 1) stage(1);

  for (int t = 0; t < nt; ++t) {
    const int buf = t % 3;
    if (t + 2 < nt) {
      stage((t + 2) % 3);
      vm_wait<2 * LT>();
    } else if (t + 1 < nt) {
      vm_wait<LT>();
    } else {
      vm_wait<0>();
    }
    __builtin_amdgcn_sched_barrier(0);
    __builtin_amdgcn_s_barrier();
    __builtin_amdgcn_sched_barrier(0);

    bf16x8 af[4], bfr[WN];
#pragma unroll
    for (int m = 0; m < 4; m++)
      af[m] = *(const bf16x8*)&lds_a[buf][(wm * 64 + m * 16 + lr) * 32 + kg * 8];
#pragma unroll
    for (int n = 0; n < WN; n++)
      bfr[n] = *(const bf16x8*)&lds_b[buf][(wn * WN * 16 + n * 16 + lr) * 32 + kg * 8];
#pragma unroll
    for (int m = 0; m < 4; m++)
#pragma unroll
      for (int n = 0; n < WN; n++)
        acc[m][n] = __builtin_amdgcn_mfma_f32_16x16x32_bf16(af[m], bfr[n], acc[m][n], 0, 0, 0);

    __builtin_amdgcn_sched_barrier(0);
    __builtin_amdgcn_s_barrier();
    __builtin_amdgcn_sched_barrier(0);
  }

  const int row0 = blockIdx.x * BM + ((BM == 128) ? wm * 64 : 0) + kg * 4;
  const int colb = colbase + wn * WN * 16;
  float* Cf = (float*)Cv + (size_t)zb * sCb + (size_t)zh * sCh;
  u16* Cu = (u16*)Cv + (size_t)zb * sCb + (size_t)zh * sCh;

  if (EPI == 0 && sel == 2) {
    // v-blocks: scatter directly into vT[(b*12+h)*64+d][s] (bit-identical values)
    u16* vTp = (u16*)res;
#pragma unroll
    for (int m = 0; m < 4; m++) {
#pragma unroll
      for (int n = 0; n < WN; n++) {
#pragma unroll
        for (int r = 0; r < 4; r++) {
          int row = row0 + m * 16 + r;          // b*1024 + s
          int col = colb + n * 16 + lr;         // 1536 + h*64 + d
          int cv = col - 1536;
          int bb = row >> 10, ss = row & 1023;
          int hh = cv >> 6, dd = cv & 63;
          vTp[(size_t)((bb * 12 + hh) * 64 + dd) * 1024 + ss] =
              f2bf(acc[m][n][r] + bias[cv]);
        }
      }
    }
    return;
  }

#pragma unroll
  for (int m = 0; m < 4; m++) {
#pragma unroll
    for (int n = 0; n < WN; n++) {
#pragma unroll
      for (int r = 0; r < 4; r++) {
        int row = row0 + m * 16 + r;
        int col = colb + n * 16 + lr;
        size_t idx = (size_t)row * ldc + col;
        float v = acc[m][n][r];
        if (EPI == 0) {
          Cu[idx] = f2bf((v + bias[col - biasoff]) * qscale);
        } else if (EPI == 1) {
          Cf[idx] = v;
        } else if (EPI == 2) {
          Cu[idx] = f2bf(v);
        } else if (EPI == 3) {
          Cf[idx] = v + bias[col] + res[idx];
        } else {  // exact GELU
          v += bias[col];
          Cu[idx] = f2bf(0.5f * v * (1.0f + erff(v * 0.70710678118654752f)));
        }
      }
    }
  }
}

extern "C" void kernel_launch(void* const* d_in, const int* in_sizes, int n_in,
                              void* d_out, int out_size, void* d_ws, size_t ws_size,
                              hipStream_t stream) {
  const float* x     = (const float*)d_in[0];
  const float* ln1_g = (const float*)d_in[1];
  const float* ln1_b = (const float*)d_in[2];
  const float* wq    = (const float*)d_in[3];
  const float* bq    = (const float*)d_in[4];
  const float* wk    = (const float*)d_in[5];
  const float* bk    = (const float*)d_in[6];
  const float* wv    = (const float*)d_in[7];
  const float* bv    = (const float*)d_in[8];
  const float* wo    = (const float*)d_in[9];
  const float* bo    = (const float*)d_in[10];
  const float* ln2_g = (const float*)d_in[11];
  const float* ln2_b = (const float*)d_in[12];
  const float* w1    = (const float*)d_in[13];
  const float* b1    = (const float*)d_in[14];
  const float* w2    = (const float*)d_in[15];
  const float* b2    = (const float*)d_in[16];
  float* out = (float*)d_out;

  char* p = (char*)d_ws;
  auto alloc = [&](size_t n) { char* r = p; p += (n + 255) & ~(size_t)255; return r; };
  u16*   qkv    = (u16*)  alloc(2048ull * 2304 * 2);       // [b*1024+s][2304] q|k (v unused)
  u16*   y1     = (u16*)  alloc(2048ull * 768 * 2);
  u16*   vT     = (u16*)  alloc(24ull * 64 * 1024 * 2);    // [(b*12+h)*64+d][1024]
  u16*   attn   = (u16*)  alloc(2048ull * 768 * 2);
  float* x1     = (float*)alloc(2048ull * 768 * 4);
  u16*   y2     = (u16*)  alloc(2048ull * 768 * 2);
  u16*   hbuf   = (u16*)  alloc(2048ull * 3072 * 2);
  u16*   pbuf   = (u16*)  alloc(4ull * 2048 * 768 * 2);    // split-K partials, bf16
  u16*   wq_t   = (u16*)  alloc(768ull * 768 * 2);
  u16*   wk_t   = (u16*)  alloc(768ull * 768 * 2);
  u16*   wv_t   = (u16*)  alloc(768ull * 768 * 2);
  u16*   wo_t   = (u16*)  alloc(768ull * 768 * 2);
  u16*   w1_t   = (u16*)  alloc(3072ull * 768 * 2);
  u16*   w2_t   = (u16*)  alloc(768ull * 3072 * 2);
  (void)in_sizes; (void)n_in; (void)out_size; (void)ws_size;

  // all weights -> bf16 [N][K] (64x64 tiles) + LN1, one dispatch (blocks 1728.. run LN1)
  wt_all<<<3776, 256, 0, stream>>>(wq, wk, wv, wo, w1, w2,
                                   wq_t, wk_t, wv_t, wo_t, w1_t, w2_t,
                                   x, ln1_g, ln1_b, y1);

  // fused QKV projection: [2048,768] x [768,2304]; q scaled by 1/8; v-blocks scatter to vT
  gemm_bt<64, 2, 0><<<dim3(32, 18, 1), 256, 0, stream>>>(
      y1, 768, 0, 0, wq_t, wk_t, wv_t, 768, 0, 0, qkv, 2304, 0, 0,
      bq, bk, bv, (const float*)vT, 768);

  // fused poly-norm attention (XCD-aware tile remap): scores never touch HBM
  fused_attn<<<dim3(64, 24), 512, 0, stream>>>(qkv, vT, attn);

  // x1 = x + attn @ wo + bo   (384 blocks)
  gemm_bt<64, 1, 3><<<dim3(32, 12, 1), 256, 0, stream>>>(
      attn, 768, 0, 0, wo_t, nullptr, nullptr, 768, 0, 0, x1, 768, 0, 0,
      bo, nullptr, nullptr, x, 768);

  // LN2
  ln_kernel<<<2048, 256, 0, stream>>>(x1, ln2_g, ln2_b, y2);

  // h = gelu(y2 @ w1 + b1)   (768 blocks = 3/CU)
  gemm_bt<64, 2, 4><<<dim3(32, 24, 1), 256, 0, stream>>>(
      y2, 768, 0, 0, w1_t, nullptr, nullptr, 768, 0, 0, hbuf, 3072, 0, 0,
      b1, nullptr, nullptr, nullptr, 768);

  // MLP2 split-K x4, bf16 partials: p[z] = h[:, z*768:(z+1)*768] @ w2_t[:, z*768:(z+1)*768]^T
  gemm_bt<64, 2, 2><<<dim3(32, 6, 4), 256, 0, stream>>>(
      hbuf, 3072, 0, 768LL, w2_t, nullptr, nullptr, 3072, 0, 768LL,
      pbuf, 768, 0, 1572864LL, nullptr, nullptr, nullptr, nullptr, 768);

  // out = sum(partials) + b2 + x1
  splitk_reduce<<<1536, 256, 0, stream>>>(pbuf, b2, x1, out);
}

// Round 18
// 155.280 us; speedup vs baseline: 1.0652x; 1.0652x over previous
//
#include <hip/hip_runtime.h>

#define DEV __device__ __forceinline__

typedef unsigned short u16;
typedef __attribute__((ext_vector_type(8))) short bf16x8;
typedef __attribute__((ext_vector_type(4))) float f32x4;
typedef __attribute__((ext_vector_type(4))) unsigned int u32x4;
typedef __attribute__((ext_vector_type(2))) unsigned int u32x2;

// round-to-nearest-even f32 -> bf16
DEV u16 f2bf(float f) {
  union { float f; unsigned u; } un; un.f = f;
  unsigned r = un.u + 0x7fffu + ((un.u >> 16) & 1u);
  return (u16)(r >> 16);
}

DEV void gload16(const void* g, void* l) {
  __builtin_amdgcn_global_load_lds((const __attribute__((address_space(1))) void*)g,
                                   (__attribute__((address_space(3))) void*)l, 16, 0, 0);
}

template <int N>
DEV void vm_wait() { asm volatile("s_waitcnt vmcnt(%0)" :: "n"(N) : "memory"); }

DEV float blk_sum(float v, volatile float* sb) {
#pragma unroll
  for (int o = 32; o; o >>= 1) v += __shfl_xor(v, o);
  __syncthreads();
  if ((threadIdx.x & 63) == 0) sb[threadIdx.x >> 6] = v;
  __syncthreads();
  return sb[0] + sb[1] + sb[2] + sb[3];
}

// ---------------- LayerNorm (row = 768) -> bf16 ----------------
__global__ __launch_bounds__(256) void ln_kernel(const float* __restrict__ x,
                                                 const float* __restrict__ g,
                                                 const float* __restrict__ b,
                                                 u16* __restrict__ y) {
  __shared__ float sb[4];
  const size_t row = blockIdx.x;
  const float* xr = x + row * 768;
  const int t = threadIdx.x;
  float v0 = xr[t], v1 = xr[t + 256], v2 = xr[t + 512];
  float mean = blk_sum(v0 + v1 + v2, sb) * (1.0f / 768.0f);
  float d0 = v0 - mean, d1 = v1 - mean, d2 = v2 - mean;
  float var = blk_sum(d0 * d0 + d1 * d1 + d2 * d2, sb) * (1.0f / 768.0f);
  float inv = rsqrtf(var + 1e-5f);
  u16* yr = y + row * 768;
  yr[t]       = f2bf(d0 * inv * g[t]       + b[t]);
  yr[t + 256] = f2bf(d1 * inv * g[t + 256] + b[t + 256]);
  yr[t + 512] = f2bf(d2 * inv * g[t + 512] + b[t + 512]);
}

// ---------------- all-weights transpose+convert + LN1, ONE dispatch ----------------
// Blocks 0..1727: 64x64 transpose tiles, in[K][N] f32 -> out[N][K] bf16.
// Blocks 1728..3775: LN1 over x rows.
__global__ __launch_bounds__(256) void wt_all(
    const float* __restrict__ wq, const float* __restrict__ wk,
    const float* __restrict__ wv, const float* __restrict__ wo,
    const float* __restrict__ w1, const float* __restrict__ w2,
    u16* __restrict__ oq, u16* __restrict__ ok, u16* __restrict__ ov,
    u16* __restrict__ oo, u16* __restrict__ o1, u16* __restrict__ o2,
    const float* __restrict__ x, const float* __restrict__ ln_g,
    const float* __restrict__ ln_b, u16* __restrict__ y1) {
  __shared__ float tile[64][65];
  __shared__ float sb[4];
  const int id = blockIdx.x;

  if (id >= 1728) {  // ---- LN1 rows ----
    const size_t row = id - 1728;
    const float* xr = x + row * 768;
    const int t = threadIdx.x;
    float v0 = xr[t], v1 = xr[t + 256], v2 = xr[t + 512];
    float mean = blk_sum(v0 + v1 + v2, sb) * (1.0f / 768.0f);
    float d0 = v0 - mean, d1 = v1 - mean, d2 = v2 - mean;
    float var = blk_sum(d0 * d0 + d1 * d1 + d2 * d2, sb) * (1.0f / 768.0f);
    float inv = rsqrtf(var + 1e-5f);
    u16* yr = y1 + row * 768;
    yr[t]       = f2bf(d0 * inv * ln_g[t]       + ln_b[t]);
    yr[t + 256] = f2bf(d1 * inv * ln_g[t + 256] + ln_b[t + 256]);
    yr[t + 512] = f2bf(d2 * inv * ln_g[t + 512] + ln_b[t + 512]);
    return;
  }

  const float* in;
  u16* out;
  int K, N, t, nx;
  if (id < 576) {
    int s = id / 144;
    t = id % 144;
    K = 768; N = 768; nx = 12;
    in  = (s == 0) ? wq : (s == 1) ? wk : (s == 2) ? wv : wo;
    out = (s == 0) ? oq : (s == 1) ? ok : (s == 2) ? ov : oo;
  } else if (id < 1152) {
    t = id - 576; in = w1; out = o1; K = 768; N = 3072; nx = 48;
  } else {
    t = id - 1152; in = w2; out = o2; K = 3072; N = 768; nx = 12;
  }
  const int yt = t / nx;
  const int xt = t - yt * nx;
  const int n0 = xt * 64, k0 = yt * 64;
  const int tx = threadIdx.x & 15, ty = threadIdx.x >> 4;  // 16 x 16

#pragma unroll
  for (int p = 0; p < 4; p++) {
    int r = p * 16 + ty;
    f32x4 v = *(const f32x4*)&in[(size_t)(k0 + r) * N + n0 + tx * 4];
    tile[r][tx * 4 + 0] = v[0];
    tile[r][tx * 4 + 1] = v[1];
    tile[r][tx * 4 + 2] = v[2];
    tile[r][tx * 4 + 3] = v[3];
  }
  __syncthreads();
#pragma unroll
  for (int p = 0; p < 4; p++) {
    int orow = p * 16 + ty;
    unsigned pk0 = (unsigned)f2bf(tile[tx * 4 + 0][orow]) |
                   ((unsigned)f2bf(tile[tx * 4 + 1][orow]) << 16);
    unsigned pk1 = (unsigned)f2bf(tile[tx * 4 + 2][orow]) |
                   ((unsigned)f2bf(tile[tx * 4 + 3][orow]) << 16);
    *(u32x2*)&out[(size_t)(n0 + orow) * K + k0 + tx * 4] = (u32x2){pk0, pk1};
  }
}

// ---------------- fused poly-norm attention (R16-proven: R9 body + T1 remap) ----------
// Grid: (64, 24) = 1536 blocks, 512 thr = 8 waves, 2 barriers. T1 remap: id2 =
// (id&7)*192 + (id>>3) gives each XCD 192 consecutive tiles = 3 heads (L2-resident K/V;
// FETCH 26.2 -> 4.7 MB, timing-neutral but free HBM savings).
// Phase 1: QK^T via MFMA -> bf16 scores scattered into swizzled 32KB LDS. BARRIER.
// Phase 2: thread owns row=tid>>5, cols (tid&31)*32..+31; Newton fully in-register,
//          half-wave shfl reduces; weights written back in place. BARRIER.
// Phase 3: waves 0..3 do PV over full K=1024; waves 4..7 exit.
// NOTE (R10/R11): tile loops inflate VGPR 32->60-80 — single tile per block.
// NOTE (R17): hand-reassociation/XOR-folded unpack REGRESSED 9us (compiler schedules
// this phase better than manual ILP surgery) — keep this exact formulation.
__global__ __launch_bounds__(512) void fused_attn(const u16* __restrict__ qkv,
                                                  const u16* __restrict__ vT,
                                                  u16* __restrict__ attn) {
  __shared__ __align__(16) u16 wlds[16 * 1024];  // 32KB, XOR-swizzled (scores, then weights)

  const int tid = threadIdx.x;
  const int w = tid >> 6, l = tid & 63;
  const int g = l >> 4, lr = l & 15;
  const int id = blockIdx.y * 64 + blockIdx.x;          // flat dispatch id (x fastest)
  const int id2 = (id & 7) * 192 + (id >> 3);           // XCD-contiguous tile id
  const int bh = id2 >> 6, b = bh / 12, h = bh % 12;
  const int q0 = (id2 & 63) * 16;

  // ---- QK^T (q pre-scaled by 1/8 in the QKV GEMM) ----
  const u16* qrow = qkv + (size_t)(b * 1024 + q0 + lr) * 2304 + h * 64;
  const u16* krow = qkv + (size_t)(b * 1024 + w * 128 + lr) * 2304 + 768 + h * 64;

  bf16x8 af[2];
  af[0] = *(const bf16x8*)(qrow + g * 8);
  af[1] = *(const bf16x8*)(qrow + 32 + g * 8);

  f32x4 acc[8];
#pragma unroll
  for (int n = 0; n < 8; n++) acc[n] = (f32x4){0.f, 0.f, 0.f, 0.f};

#pragma unroll
  for (int n = 0; n < 8; n++) {
    bf16x8 b0 = *(const bf16x8*)(krow + n * 16 * 2304 + g * 8);
    bf16x8 b1 = *(const bf16x8*)(krow + n * 16 * 2304 + 32 + g * 8);
    acc[n] = __builtin_amdgcn_mfma_f32_16x16x32_bf16(af[0], b0, acc[n], 0, 0, 0);
    acc[n] = __builtin_amdgcn_mfma_f32_16x16x32_bf16(af[1], b1, acc[n], 0, 0, 0);
  }
  // lane holds scores for rows g*4 + r (q-local), cols w*128 + n*16 + lr

  // ---- scatter scores (bf16) into swizzled LDS ----
#pragma unroll
  for (int n = 0; n < 8; n++)
#pragma unroll
    for (int r = 0; r < 4; r++) {
      int row = g * 4 + r;
      int col = w * 128 + n * 16 + lr;
      unsigned off = (unsigned)(row * 2048 + col * 2);
      off ^= (unsigned)(row & 7) << 4;
      *(u16*)((char*)wlds + off) = f2bf(acc[n][r]);
    }
  __syncthreads();  // barrier 1

  // ---- chunk read: thread owns row = tid>>5, cols (tid&31)*32 .. +31 ----
  const int crow = tid >> 5, l32 = tid & 31;
  const unsigned cswz = (unsigned)(crow & 7) << 4;
  const unsigned cbase = (unsigned)(crow * 2048 + l32 * 64);
  float xs[32];
#pragma unroll
  for (int j = 0; j < 4; j++) {
    u32x4 raw = *(const u32x4*)((const char*)wlds + ((cbase + j * 16u) ^ cswz));
#pragma unroll
    for (int e = 0; e < 4; e++) {
      union { unsigned u; float f; } lo, hi;
      lo.u = raw[e] << 16;
      hi.u = raw[e] & 0xffff0000u;
      xs[j * 8 + e * 2] = lo.f;
      xs[j * 8 + e * 2 + 1] = hi.f;
    }
  }

  // ---- row max (31 fmax + 5 half-wave shfl) -> c0 = -max - 1 ----
  float mx = xs[0];
#pragma unroll
  for (int i = 1; i < 32; i++) mx = fmaxf(mx, xs[i]);
#pragma unroll
  for (int o = 1; o < 32; o <<= 1) mx = fmaxf(mx, __shfl_xor(mx, o));
  float c = -mx - 1.0f;

  // ---- 6 Newton iterations: fully in-register, zero barriers ----
#pragma unroll 1
  for (int it = 0; it < 6; it++) {
    float s2 = 0.f, s3 = 0.f;
#pragma unroll
    for (int i = 0; i < 32; i++) {
      float rr = __builtin_amdgcn_rcpf(-(xs[i] + c));  // 1/base, base >= 1
      float r2 = rr * rr;
      s2 += r2;
      s3 = fmaf(r2, rr, s3);
    }
#pragma unroll
    for (int o = 1; o < 32; o <<= 1) {
      s2 += __shfl_xor(s2, o);
      s3 += __shfl_xor(s3, o);
    }
    c -= (s2 - 1.0f) * __builtin_amdgcn_rcpf(2.0f * s3 + 1e-8f);
  }

  // ---- weights = base^-2 -> bf16, written back in place (same addresses) ----
#pragma unroll
  for (int j = 0; j < 4; j++) {
    u32x4 outv;
#pragma unroll
    for (int e = 0; e < 4; e++) {
      float r0 = __builtin_amdgcn_rcpf(-(xs[j * 8 + e * 2] + c));
      float r1 = __builtin_amdgcn_rcpf(-(xs[j * 8 + e * 2 + 1] + c));
      outv[e] = (unsigned)f2bf(r0 * r0) | ((unsigned)f2bf(r1 * r1) << 16);
    }
    *(u32x4*)((char*)wlds + ((cbase + j * 16u) ^ cswz)) = outv;
  }
  __syncthreads();  // barrier 2

  // ---- PV: waves 0..3 only — wave w: O[16][w*16..+16] over full K=1024 ----
  if (w < 4) {
    const int nf = w;
    const u16* vrow = vT + (size_t)(bh * 64 + nf * 16 + lr) * 1024;
    const unsigned swz = (unsigned)(lr & 7) << 4;
    const unsigned abase = (unsigned)(lr * 2048);
    f32x4 oacc = (f32x4){0.f, 0.f, 0.f, 0.f};
#pragma unroll
    for (int ks = 0; ks < 32; ks++) {
      // full-address XOR matching the write-side involution
      bf16x8 afr = *(const bf16x8*)((const char*)wlds +
                                    ((abase + (unsigned)(ks * 64 + g * 16)) ^ swz));
      bf16x8 bfr = *(const bf16x8*)(vrow + ks * 32 + g * 8);
      oacc = __builtin_amdgcn_mfma_f32_16x16x32_bf16(afr, bfr, oacc, 0, 0, 0);
    }
    u16* orow = attn + (size_t)(b * 1024 + q0 + g * 4) * 768 + h * 64 + nf * 16 + lr;
#pragma unroll
    for (int r = 0; r < 4; r++) orow[(size_t)r * 768] = f2bf(oacc[r]);
  }
}

// ---------------- split-K reduce (bf16 partials): out = sum(p[z]) + bias + res ----------------
__global__ __launch_bounds__(256) void splitk_reduce(const u16* __restrict__ p,
                                                     const float* __restrict__ bias,
                                                     const float* __restrict__ res,
                                                     float* __restrict__ out) {
  const size_t S = 2048ull * 768;
  size_t i = ((size_t)blockIdx.x * 256 + threadIdx.x) * 4;
  float a0 = 0.f, a1 = 0.f, a2 = 0.f, a3 = 0.f;
#pragma unroll
  for (int z = 0; z < 4; z++) {
    u32x2 raw = *(const u32x2*)&p[i + z * S];
    union { unsigned u; float f; } v0, v1, v2, v3;
    v0.u = raw[0] << 16;
    v1.u = raw[0] & 0xffff0000u;
    v2.u = raw[1] << 16;
    v3.u = raw[1] & 0xffff0000u;
    a0 += v0.f; a1 += v1.f; a2 += v2.f; a3 += v3.f;
  }
  int col = (int)(i % 768);
  f32x4 bv = *(const f32x4*)&bias[col];
  f32x4 rv = *(const f32x4*)&res[i];
  f32x4 v = (f32x4){a0, a1, a2, a3} + bv + rv;
  *(f32x4*)&out[i] = v;
}

// ---------------- pipelined MFMA GEMM: C = A[M][K] * Bt[N][K]^T ----------------
// BM in {64,128}. BM=128: 4 waves as 2x2, BN = 2*WN*16. BM=64: 4 waves as 1x4, BN = 4*WN*16.
// 3-buffer LDS, 2-deep global_load_lds prefetch, counted vmcnt, raw s_barrier (no drain).
// EPI: 0=fused QKV (bias-select + q scale, bf16 out; v-blocks scatter into vT via 'res'),
//      1=f32 plain, 2=bf16 plain, 3=f32 + bias + residual, 4=GELU(acc+bias) bf16
template <int BM, int WN, int EPI>
__global__ __launch_bounds__(256) void gemm_bt(
    const u16* __restrict__ A, int lda, long long sAb, long long sAh,
    const u16* __restrict__ B0, const u16* __restrict__ B1, const u16* __restrict__ B2,
    int ldb, long long sBb, long long sBh,
    void* __restrict__ Cv, int ldc, long long sCb, long long sCh,
    const float* __restrict__ bias0, const float* __restrict__ bias1,
    const float* __restrict__ bias2, const float* __restrict__ res, int K) {
  constexpr int WCOL = (BM == 128) ? 2 : 4;
  constexpr int BN = WCOL * WN * 16;
  constexpr int NA = BM / 64;
  constexpr int NB = BN / 64;
  constexpr int LT = NA + NB;
  __shared__ __align__(16) u16 lds_a[3][BM * 32];
  __shared__ __align__(16) u16 lds_b[3][BN * 32];

  const int zb = blockIdx.z / 12, zh = blockIdx.z % 12;
  A += zb * sAb + zh * sAh;

  const int colbase = blockIdx.y * BN;
  const u16* B = B0;
  const float* bias = bias0;
  int biasoff = 0;
  float qscale = 1.0f;
  int sel = 0;
  if (EPI == 0) {
    sel = colbase / 768;
    B = (sel == 0) ? B0 : ((sel == 1) ? B1 : B2);
    bias = (sel == 0) ? bias0 : ((sel == 1) ? bias1 : bias2);
    biasoff = sel * 768;
    qscale = (sel == 0) ? 0.125f : 1.0f;  // 1/sqrt(64) on q only
  }
  B += zb * sBb + zh * sBh;

  const int tid = threadIdx.x;
  const size_t ldab = (size_t)lda * 2, ldbb = (size_t)ldb * 2;
  const char* Abase = (const char*)(A + (size_t)blockIdx.x * BM * lda);
  const char* Bbase = (const char*)(B + (size_t)(colbase - biasoff) * ldb);

  const char* ap[NA];
  const char* bp[NB];
#pragma unroll
  for (int j = 0; j < NA; j++) {
    int lin = (j * 256 + tid) * 16;
    ap[j] = Abase + (size_t)(lin >> 6) * ldab + (lin & 63);
  }
#pragma unroll
  for (int j = 0; j < NB; j++) {
    int lin = (j * 256 + tid) * 16;
    bp[j] = Bbase + (size_t)(lin >> 6) * ldbb + (lin & 63);
  }

  auto stage = [&](int buf) {
#pragma unroll
    for (int j = 0; j < NA; j++) {
      gload16(ap[j], (char*)&lds_a[buf][0] + (j * 256 + tid) * 16);
      ap[j] += 64;
    }
#pragma unroll
    for (int j = 0; j < NB; j++) {
      gload16(bp[j], (char*)&lds_b[buf][0] + (j * 256 + tid) * 16);
      bp[j] += 64;
    }
  };

  f32x4 acc[4][WN];
#pragma unroll
  for (int m = 0; m < 4; m++)
#pragma unroll
    for (int n = 0; n < WN; n++) acc[m][n] = (f32x4){0.f, 0.f, 0.f, 0.f};

  const int w = tid >> 6, l = tid & 63;
  const int wm = (BM == 128) ? (w >> 1) : 0;
  const int wn = (BM == 128) ? (w & 1) : w;
  const int lr = l & 15, kg = l >> 4;

  const int nt = K / 32;
  stage(0);
  if (nt > 1) stage(1);

  for (int t = 0; t < nt; ++t) {
    const int buf = t % 3;
    if (t + 2 < nt) {
      stage((t + 2) % 3);
      vm_wait<2 * LT>();
    } else if (t + 1 < nt) {
      vm_wait<LT>();
    } else {
      vm_wait<0>();
    }
    __builtin_amdgcn_sched_barrier(0);
    __builtin_amdgcn_s_barrier();
    __builtin_amdgcn_sched_barrier(0);

    bf16x8 af[4], bfr[WN];
#pragma unroll
    for (int m = 0; m < 4; m++)
      af[m] = *(const bf16x8*)&lds_a[buf][(wm * 64 + m * 16 + lr) * 32 + kg * 8];
#pragma unroll
    for (int n = 0; n < WN; n++)
      bfr[n] = *(const bf16x8*)&lds_b[buf][(wn * WN * 16 + n * 16 + lr) * 32 + kg * 8];
#pragma unroll
    for (int m = 0; m < 4; m++)
#pragma unroll
      for (int n = 0; n < WN; n++)
        acc[m][n] = __builtin_amdgcn_mfma_f32_16x16x32_bf16(af[m], bfr[n], acc[m][n], 0, 0, 0);

    __builtin_amdgcn_sched_barrier(0);
    __builtin_amdgcn_s_barrier();
    __builtin_amdgcn_sched_barrier(0);
  }

  const int row0 = blockIdx.x * BM + ((BM == 128) ? wm * 64 : 0) + kg * 4;
  const int colb = colbase + wn * WN * 16;
  float* Cf = (float*)Cv + (size_t)zb * sCb + (size_t)zh * sCh;
  u16* Cu = (u16*)Cv + (size_t)zb * sCb + (size_t)zh * sCh;

  if (EPI == 0 && sel == 2) {
    // v-blocks: scatter directly into vT[(b*12+h)*64+d][s] (bit-identical values)
    u16* vTp = (u16*)res;
#pragma unroll
    for (int m = 0; m < 4; m++) {
#pragma unroll
      for (int n = 0; n < WN; n++) {
#pragma unroll
        for (int r = 0; r < 4; r++) {
          int row = row0 + m * 16 + r;          // b*1024 + s
          int col = colb + n * 16 + lr;         // 1536 + h*64 + d
          int cv = col - 1536;
          int bb = row >> 10, ss = row & 1023;
          int hh = cv >> 6, dd = cv & 63;
          vTp[(size_t)((bb * 12 + hh) * 64 + dd) * 1024 + ss] =
              f2bf(acc[m][n][r] + bias[cv]);
        }
      }
    }
    return;
  }

#pragma unroll
  for (int m = 0; m < 4; m++) {
#pragma unroll
    for (int n = 0; n < WN; n++) {
#pragma unroll
      for (int r = 0; r < 4; r++) {
        int row = row0 + m * 16 + r;
        int col = colb + n * 16 + lr;
        size_t idx = (size_t)row * ldc + col;
        float v = acc[m][n][r];
        if (EPI == 0) {
          Cu[idx] = f2bf((v + bias[col - biasoff]) * qscale);
        } else if (EPI == 1) {
          Cf[idx] = v;
        } else if (EPI == 2) {
          Cu[idx] = f2bf(v);
        } else if (EPI == 3) {
          Cf[idx] = v + bias[col] + res[idx];
        } else {  // exact GELU
          v += bias[col];
          Cu[idx] = f2bf(0.5f * v * (1.0f + erff(v * 0.70710678118654752f)));
        }
      }
    }
  }
}

extern "C" void kernel_launch(void* const* d_in, const int* in_sizes, int n_in,
                              void* d_out, int out_size, void* d_ws, size_t ws_size,
                              hipStream_t stream) {
  const float* x     = (const float*)d_in[0];
  const float* ln1_g = (const float*)d_in[1];
  const float* ln1_b = (const float*)d_in[2];
  const float* wq    = (const float*)d_in[3];
  const float* bq    = (const float*)d_in[4];
  const float* wk    = (const float*)d_in[5];
  const float* bk    = (const float*)d_in[6];
  const float* wv    = (const float*)d_in[7];
  const float* bv    = (const float*)d_in[8];
  const float* wo    = (const float*)d_in[9];
  const float* bo    = (const float*)d_in[10];
  const float* ln2_g = (const float*)d_in[11];
  const float* ln2_b = (const float*)d_in[12];
  const float* w1    = (const float*)d_in[13];
  const float* b1    = (const float*)d_in[14];
  const float* w2    = (const float*)d_in[15];
  const float* b2    = (const float*)d_in[16];
  float* out = (float*)d_out;

  char* p = (char*)d_ws;
  auto alloc = [&](size_t n) { char* r = p; p += (n + 255) & ~(size_t)255; return r; };
  u16*   qkv    = (u16*)  alloc(2048ull * 2304 * 2);       // [b*1024+s][2304] q|k (v unused)
  u16*   y1     = (u16*)  alloc(2048ull * 768 * 2);
  u16*   vT     = (u16*)  alloc(24ull * 64 * 1024 * 2);    // [(b*12+h)*64+d][1024]
  u16*   attn   = (u16*)  alloc(2048ull * 768 * 2);
  float* x1     = (float*)alloc(2048ull * 768 * 4);
  u16*   y2     = (u16*)  alloc(2048ull * 768 * 2);
  u16*   hbuf   = (u16*)  alloc(2048ull * 3072 * 2);
  u16*   pbuf   = (u16*)  alloc(4ull * 2048 * 768 * 2);    // split-K partials, bf16
  u16*   wq_t   = (u16*)  alloc(768ull * 768 * 2);
  u16*   wk_t   = (u16*)  alloc(768ull * 768 * 2);
  u16*   wv_t   = (u16*)  alloc(768ull * 768 * 2);
  u16*   wo_t   = (u16*)  alloc(768ull * 768 * 2);
  u16*   w1_t   = (u16*)  alloc(3072ull * 768 * 2);
  u16*   w2_t   = (u16*)  alloc(768ull * 3072 * 2);
  (void)in_sizes; (void)n_in; (void)out_size; (void)ws_size;

  // all weights -> bf16 [N][K] (64x64 tiles) + LN1, one dispatch (blocks 1728.. run LN1)
  wt_all<<<3776, 256, 0, stream>>>(wq, wk, wv, wo, w1, w2,
                                   wq_t, wk_t, wv_t, wo_t, w1_t, w2_t,
                                   x, ln1_g, ln1_b, y1);

  // fused QKV projection: [2048,768] x [768,2304]; q scaled by 1/8; v-blocks scatter to vT
  gemm_bt<64, 2, 0><<<dim3(32, 18, 1), 256, 0, stream>>>(
      y1, 768, 0, 0, wq_t, wk_t, wv_t, 768, 0, 0, qkv, 2304, 0, 0,
      bq, bk, bv, (const float*)vT, 768);

  // fused poly-norm attention (XCD-aware tile remap): scores never touch HBM
  fused_attn<<<dim3(64, 24), 512, 0, stream>>>(qkv, vT, attn);

  // x1 = x + attn @ wo + bo   (384 blocks)
  gemm_bt<64, 1, 3><<<dim3(32, 12, 1), 256, 0, stream>>>(
      attn, 768, 0, 0, wo_t, nullptr, nullptr, 768, 0, 0, x1, 768, 0, 0,
      bo, nullptr, nullptr, x, 768);

  // LN2
  ln_kernel<<<2048, 256, 0, stream>>>(x1, ln2_g, ln2_b, y2);

  // h = gelu(y2 @ w1 + b1)   (768 blocks = 3/CU)
  gemm_bt<64, 2, 4><<<dim3(32, 24, 1), 256, 0, stream>>>(
      y2, 768, 0, 0, w1_t, nullptr, nullptr, 768, 0, 0, hbuf, 3072, 0, 0,
      b1, nullptr, nullptr, nullptr, 768);

  // MLP2 split-K x4, bf16 partials: p[z] = h[:, z*768:(z+1)*768] @ w2_t[:, z*768:(z+1)*768]^T
  gemm_bt<64, 2, 2><<<dim3(32, 6, 4), 256, 0, stream>>>(
      hbuf, 3072, 0, 768LL, w2_t, nullptr, nullptr, 3072, 0, 768LL,
      pbuf, 768, 0, 1572864LL, nullptr, nullptr, nullptr, nullptr, 768);

  // out = sum(partials) + b2 + x1
  splitk_reduce<<<1536, 256, 0, stream>>>(pbuf, b2, x1, out);
}